// Round 6
// baseline (317.386 us; speedup 1.0000x reference)
//
#include <hip/hip_runtime.h>
#include <hip/hip_bf16.h>
#include <stdint.h>

// Problem constants
#define BSZ 256
#define NQ 4096
#define K1 2048
#define N1P 8448         // P stride: 32 groups x 264 cols [qkv_half 4096 | gate 4096 | alpha 32 | beta 32 | pad]
#define N3 2048
#define K3 4096

typedef __attribute__((ext_vector_type(8))) short bf16x8;
typedef __attribute__((ext_vector_type(4))) float f32x4;

__device__ __forceinline__ unsigned short f2bf(float f) {
  union { float f; unsigned u; } v; v.f = f;
  unsigned r = v.u + 0x7fffu + ((v.u >> 16) & 1u);   // RNE
  return (unsigned short)(r >> 16);
}

__device__ __forceinline__ bf16x8 pack8(float4 a, float4 b) {
  union { bf16x8 v; unsigned short u[8]; } o;
  o.u[0] = f2bf(a.x); o.u[1] = f2bf(a.y); o.u[2] = f2bf(a.z); o.u[3] = f2bf(a.w);
  o.u[4] = f2bf(b.x); o.u[5] = f2bf(b.y); o.u[6] = f2bf(b.z); o.u[7] = f2bf(b.w);
  return o.v;
}

// ---------------- K0: hidden fp32 -> bf16 ----------------
__global__ __launch_bounds__(256) void cvt_kernel(const float* __restrict__ x,
                                                  unsigned short* __restrict__ y) {
  int i = (blockIdx.x * 256 + threadIdx.x) * 8;
  float4 a = *(const float4*)(x + i);
  float4 b = *(const float4*)(x + i + 4);
  ushort4 o0 = { f2bf(a.x), f2bf(a.y), f2bf(a.z), f2bf(a.w) };
  ushort4 o1 = { f2bf(b.x), f2bf(b.y), f2bf(b.z), f2bf(b.w) };
  *(ushort4*)(y + i) = o0;
  *(ushort4*)(y + i + 4) = o1;
}

// B-row base for the packed [qkv_half | gate | alpha | beta | pad] column space
__device__ __forceinline__ const float* brow1(int col, const float* Wqkv, const float* Wgate,
                                              const float* Wa, const float* Wb) {
  if (col < 4096) return Wqkv + (size_t)(4096 + col) * K1;
  if (col < 8192) return Wgate + (size_t)(col - 4096) * K1;
  if (col < 8224) return Wa + (size_t)(col - 8192) * K1;
  if (col < 8256) return Wb + (size_t)(col - 8224) * K1;
  return Wa;   // pad cols: junk, guarded at store
}

// ---------------- K1: GEMM1  P += hidden @ [Wqkv_half;Wgate;Walpha;Wbeta]^T ----------------
// 256 blocks (32 Ngroups x 8 Ksplits), 512 thr = 8 waves (4M x 2N), 1 block/CU.
// A-fragments persistent in registers (128 VGPR); B streamed global->reg->pack; no LDS/barriers.
__global__ __launch_bounds__(512) void gemm1_kernel(
    const unsigned short* __restrict__ A16,   // [256][2048] bf16
    const float* __restrict__ Wqkv, const float* __restrict__ Wgate,
    const float* __restrict__ Walpha, const float* __restrict__ Wbeta,
    float* __restrict__ P) {                  // [256][8448] fp32, zeroed (atomic accum)
  const int tid = threadIdx.x, lane = tid & 63, wv = tid >> 6;
  const int wm = wv >> 1, wc = wv & 1;        // wave grid: 4 (M) x 2 (N)
  const int l15 = lane & 15, q = lane >> 4;
  const int nbase = blockIdx.x * 264;
  const int kb = blockIdx.y * 256;

  // B step-0 loads first (HBM stream starts immediately)
  float4 bst[8][2];
  {
    int col = nbase + wc * 16 + l15;
    const float* bp = brow1(col, Wqkv, Wgate, Walpha, Wbeta) + kb + q * 8;
#pragma unroll
    for (int ks = 0; ks < 8; ks++) {
      bst[ks][0] = *(const float4*)(bp + ks * 32);
      bst[ks][1] = *(const float4*)(bp + ks * 32 + 4);
    }
  }

  // Persistent A-fragments: rows wm*64 .. wm*64+63, k in [kb, kb+256)
  bf16x8 aF[4][8];
  {
    const unsigned short* aBase = A16 + (size_t)(wm * 64 + l15) * K1 + kb + q * 8;
#pragma unroll
    for (int i = 0; i < 4; i++)
#pragma unroll
      for (int ks = 0; ks < 8; ks++)
        aF[i][ks] = *(const bf16x8*)(aBase + (size_t)i * 16 * K1 + ks * 32);
  }

#pragma unroll 1
  for (int s = 0; s < 9; s++) {
    f32x4 acc[4];
#pragma unroll
    for (int i = 0; i < 4; i++) { f32x4 z = {0.f, 0.f, 0.f, 0.f}; acc[i] = z; }
#pragma unroll
    for (int ks = 0; ks < 8; ks++) {
      bf16x8 bF = pack8(bst[ks][0], bst[ks][1]);
#pragma unroll
      for (int i = 0; i < 4; i++)
        acc[i] = __builtin_amdgcn_mfma_f32_16x16x32_bf16(aF[i][ks], bF, acc[i], 0, 0, 0);
    }
    // issue next step's B loads (regs free after packs)
    if (s + 1 < 9) {
      int col = nbase + (s + 1) * 32 + wc * 16 + l15;
      const float* bp = brow1(col, Wqkv, Wgate, Walpha, Wbeta) + kb + q * 8;
#pragma unroll
      for (int ks = 0; ks < 8; ks++) {
        bst[ks][0] = *(const float4*)(bp + ks * 32);
        bst[ks][1] = *(const float4*)(bp + ks * 32 + 4);
      }
    }
    // flush accumulator (guard tail: local col must be < 264)
    int lcol = s * 32 + wc * 16 + l15;
    if (lcol < 264) {
      int col = nbase + lcol;
#pragma unroll
      for (int i = 0; i < 4; i++) {
        int row = wm * 64 + i * 16 + q * 4;
#pragma unroll
        for (int r = 0; r < 4; r++)
          atomicAdd(&P[(size_t)(row + r) * N1P + col], acc[i][r]);
      }
    }
  }
}

// ---------------- K2: per-row fused conv + SSM + RMS + gate; writes core bf16 ----------------
__global__ __launch_bounds__(1024) void fuse_kernel(
    const float* __restrict__ P,        // [256][8448]
    const float* __restrict__ bqkv,     // [8192]
    const float* __restrict__ ck,       // [8192][4]
    const float* __restrict__ cstate,   // [256][4][8192]
    const float* __restrict__ ssa,      // [32]
    const float* __restrict__ dtb,      // [32]
    const float* __restrict__ nw,       // [128]
    const float* __restrict__ sstate,   // [256][32]
    unsigned short* __restrict__ C16) { // [256][4096] bf16
  __shared__ float gsum[64];
  __shared__ float ssl[32];
  __shared__ float red[20];
  const int b = blockIdx.x, tid = threadIdx.x;
  const int lane = tid & 63, wv = tid >> 6;
  const float* Pb = P + (size_t)b * N1P;
  const int j = tid * 4;

  // prefetch gate operands (used in pass 3)
  float4 gx = *(const float4*)(Pb + NQ + j);

  if (wv == 0) {   // mean(ssm_norm_weight)
    float m = nw[lane] + nw[lane + 64];
#pragma unroll
    for (int off = 32; off; off >>= 1) m += __shfl_down(m, off, 64);
    if (lane == 0) red[16] = m * (1.f / 128.f);
  }

  // pass 1: core_base (conv) + group sums via 16-lane shuffle reduce
  float4 qv = *(const float4*)(Pb + j);
  float4 bq = *(const float4*)(bqkv + NQ + j);
  float mqx = qv.x + bq.x, mqy = qv.y + bq.y, mqz = qv.z + bq.z, mqw = qv.w + bq.w;
  const float* csb = cstate + (size_t)b * 4 * 8192 + NQ + j;
  float4 c1 = *(const float4*)(csb + 8192);
  float4 c2 = *(const float4*)(csb + 16384);
  float4 c3 = *(const float4*)(csb + 24576);
  float4 k0v = *(const float4*)(ck + (size_t)(NQ + j) * 4);
  float4 k1v = *(const float4*)(ck + (size_t)(NQ + j + 1) * 4);
  float4 k2v = *(const float4*)(ck + (size_t)(NQ + j + 2) * 4);
  float4 k3v = *(const float4*)(ck + (size_t)(NQ + j + 3) * 4);
  float4 cbv;
  cbv.x = c1.x * k0v.x + c2.x * k0v.y + c3.x * k0v.z + mqx * k0v.w;
  cbv.y = c1.y * k1v.x + c2.y * k1v.y + c3.y * k1v.z + mqy * k1v.w;
  cbv.z = c1.z * k2v.x + c2.z * k2v.y + c3.z * k2v.z + mqz * k2v.w;
  cbv.w = c1.w * k3v.x + c2.w * k3v.y + c3.w * k3v.z + mqw * k3v.w;
  {
    float s = cbv.x + cbv.y + cbv.z + cbv.w;
    s += __shfl_xor(s, 1, 64); s += __shfl_xor(s, 2, 64);
    s += __shfl_xor(s, 4, 64); s += __shfl_xor(s, 8, 64);
    if ((lane & 15) == 0) gsum[tid >> 4] = s;
  }
  __syncthreads();

  if (tid < 32) {
    float a  = Pb[8192 + tid];
    float bc = Pb[8224 + tid];
    float kg = gsum[tid] * (1.f / 64.f);
    float vg = gsum[32 + tid] * (1.f / 64.f);
    float x = a + dtb[tid];
    float sp = fmaxf(x, 0.f) + log1pf(expf(-fabsf(x)));   // stable softplus
    float g = -expf(ssa[tid]) * sp;
    float beta = 1.f / (1.f + expf(-bc));
    float ns = expf(g) * sstate[b * 32 + tid] + beta * vg;
    ssl[tid] = ns / (1.f + expf(-kg));
  }
  __syncthreads();

  // pass 2: core1 = core_base + expanded; sum of squares
  float sv = ssl[j >> 7];
  float4 v = cbv;
  v.x += sv; v.y += sv; v.z += sv; v.w += sv;
  float sq = v.x * v.x + v.y * v.y + v.z * v.z + v.w * v.w;
#pragma unroll
  for (int off = 32; off; off >>= 1) sq += __shfl_down(sq, off, 64);
  if (lane == 0) red[wv] = sq;
  __syncthreads();
  if (tid == 0) {
    float t = 0.f;
#pragma unroll
    for (int w = 0; w < 16; w++) t += red[w];
    red[17] = rsqrtf(t * (1.f / 4096.f) + 1e-6f);
  }
  __syncthreads();
  float rms = red[17], mwv = red[16];

  // pass 3: apply gate, write bf16
  float ox = v.x * rms * mwv / (1.f + expf(-gx.x));
  float oy = v.y * rms * mwv / (1.f + expf(-gx.y));
  float oz = v.z * rms * mwv / (1.f + expf(-gx.z));
  float ow = v.w * rms * mwv / (1.f + expf(-gx.w));
  ushort4 u = { f2bf(ox), f2bf(oy), f2bf(oz), f2bf(ow) };
  *(ushort4*)(C16 + (size_t)b * 4096 + j) = u;
}

// ---------------- K3: GEMM3  out += core @ Wout^T ----------------
// 256 blocks (8 Ngroups x 32 Ksplits), Kchunk=128, same register-persistent structure.
__global__ __launch_bounds__(512) void gemm3_kernel(
    const unsigned short* __restrict__ C16,  // [256][4096] bf16
    const float* __restrict__ Wout,          // [2048][4096] fp32
    float* __restrict__ out) {               // [256][2048] fp32, zeroed (atomic accum)
  const int tid = threadIdx.x, lane = tid & 63, wv = tid >> 6;
  const int wm = wv >> 1, wc = wv & 1;
  const int l15 = lane & 15, q = lane >> 4;
  const int nbase = blockIdx.x * 256;
  const int kb = blockIdx.y * 128;

  float4 bst[4][2];
  {
    const float* bp = Wout + (size_t)(nbase + wc * 16 + l15) * K3 + kb + q * 8;
#pragma unroll
    for (int ks = 0; ks < 4; ks++) {
      bst[ks][0] = *(const float4*)(bp + ks * 32);
      bst[ks][1] = *(const float4*)(bp + ks * 32 + 4);
    }
  }

  bf16x8 aF[4][4];
  {
    const unsigned short* aBase = C16 + (size_t)(wm * 64 + l15) * K3 + kb + q * 8;
#pragma unroll
    for (int i = 0; i < 4; i++)
#pragma unroll
      for (int ks = 0; ks < 4; ks++)
        aF[i][ks] = *(const bf16x8*)(aBase + (size_t)i * 16 * K3 + ks * 32);
  }

#pragma unroll 1
  for (int s = 0; s < 8; s++) {
    f32x4 acc[4];
#pragma unroll
    for (int i = 0; i < 4; i++) { f32x4 z = {0.f, 0.f, 0.f, 0.f}; acc[i] = z; }
#pragma unroll
    for (int ks = 0; ks < 4; ks++) {
      bf16x8 bF = pack8(bst[ks][0], bst[ks][1]);
#pragma unroll
      for (int i = 0; i < 4; i++)
        acc[i] = __builtin_amdgcn_mfma_f32_16x16x32_bf16(aF[i][ks], bF, acc[i], 0, 0, 0);
    }
    if (s + 1 < 8) {
      const float* bp = Wout + (size_t)(nbase + (s + 1) * 32 + wc * 16 + l15) * K3 + kb + q * 8;
#pragma unroll
      for (int ks = 0; ks < 4; ks++) {
        bst[ks][0] = *(const float4*)(bp + ks * 32);
        bst[ks][1] = *(const float4*)(bp + ks * 32 + 4);
      }
    }
    int col = nbase + s * 32 + wc * 16 + l15;
#pragma unroll
    for (int i = 0; i < 4; i++) {
      int row = wm * 64 + i * 16 + q * 4;
#pragma unroll
      for (int r = 0; r < 4; r++)
        atomicAdd(&out[(size_t)(row + r) * N3 + col], acc[i][r]);
    }
  }
}

extern "C" void kernel_launch(void* const* d_in, const int* in_sizes, int n_in,
                              void* d_out, int out_size, void* d_ws, size_t ws_size,
                              hipStream_t stream) {
  const float* hidden = (const float*)d_in[0];
  const float* Wqkv   = (const float*)d_in[1];
  const float* bqkv   = (const float*)d_in[2];
  const float* Wgate  = (const float*)d_in[3];
  const float* Walpha = (const float*)d_in[4];
  const float* Wbeta  = (const float*)d_in[5];
  const float* Wout   = (const float*)d_in[6];
  const float* ssa    = (const float*)d_in[7];
  const float* dtb    = (const float*)d_in[8];
  const float* nw     = (const float*)d_in[9];
  const float* ck     = (const float*)d_in[10];
  const float* sstate = (const float*)d_in[11];
  const float* cstate = (const float*)d_in[12];
  float* out = (float*)d_out;

  char* ws = (char*)d_ws;
  unsigned short* A16 = (unsigned short*)ws;                           // 1 MB
  float* P = (float*)(ws + (1 << 20));                                 // 256*8448*4 = 8,650,752 B
  unsigned short* C16 = (unsigned short*)(ws + (1 << 20) + 8650752);   // 2 MB

  hipMemsetAsync(P, 0, (size_t)BSZ * N1P * sizeof(float), stream);
  hipMemsetAsync(out, 0, (size_t)BSZ * N3 * sizeof(float), stream);
  cvt_kernel<<<256, 256, 0, stream>>>(hidden, A16);
  gemm1_kernel<<<dim3(32, 8), 512, 0, stream>>>(A16, Wqkv, Wgate, Walpha, Wbeta, P);
  fuse_kernel<<<256, 1024, 0, stream>>>(P, bqkv, ck, cstate, ssa, dtb, nw, sstate, C16);
  gemm3_kernel<<<dim3(8, 32), 512, 0, stream>>>(C16, Wout, out);
}